// Round 1
// baseline (172.202 us; speedup 1.0000x reference)
//
#include <hip/hip_runtime.h>
#include <hip/hip_bf16.h>
#include <stdint.h>

#define NROWS 16384
#define NDIM  1024
#define NLAB  64
#define NC    65
#define CPAD  80

typedef float float4v __attribute__((ext_vector_type(4)));
typedef short short8  __attribute__((ext_vector_type(8)));

// ---- workspace layout (bytes); nothing needs pre-zeroing ----
static constexpr size_t SCALE_B = 0;         // 80 f32 (w/||abf_c||)
static constexpr size_t ACTB_B  = 320;       // 80 u8 active flags
static constexpr size_t WSUM_B  = 400;       // f32 loss accumulator (zeroed by k2bB)
static constexpr size_t CNTF_B  = 448;       // 80 u32 counts (written by k2bB)
static constexpr size_t CNTP_B  = 1024;      // 256 x 80 u32 per-block count slabs
static constexpr size_t MASK_B  = 83968;     // 16384 u64 row masks
static constexpr size_t XN2_B   = 215040;    // 16384 f32 row norms^2
static constexpr size_t LFRAG_B = 280576;    // labT bf16, A-frag layout (2.6 MB)
static constexpr size_t BFRAG_B = 2902016;   // unit anchors bf16, B-frag layout
static constexpr size_t XAF_B   = 3065856;   // x bf16, A-frag layout (32 MB)
static constexpr size_t XCOL_B  = 36620288;  // x bf16, col-major 16-row tiles (32 MB)
static constexpr size_t PART_B  = 70174720;  // kslices*80*1024 f32 partials
static constexpr size_t SLAB    = (size_t)CPAD * NDIM * 4;
static constexpr size_t ANCH_SZ = (size_t)CPAD * NDIM * 4;   // raw anchor sums f32
static constexpr size_t NRM_SZ  = (size_t)CPAD * 4 * 4;      // 320 f32 norm2 partials

__device__ __forceinline__ unsigned short bf16u(float f) {
    __hip_bfloat16 h = __float2bfloat16(f);
    return __builtin_bit_cast(unsigned short, h);
}
__device__ __forceinline__ unsigned pk2(float a, float b) {
    return (unsigned)bf16u(a) | ((unsigned)bf16u(b) << 16);
}

// ---- K01: blocks 0..1023 = x prep (xAfrag/xcol/xn2); 1024..1279 = labels ----
__global__ __launch_bounds__(256) void k01_prep(const float* __restrict__ x,
                                                const int* __restrict__ label,
                                                unsigned short* __restrict__ xAfrag,
                                                unsigned short* __restrict__ xcol,
                                                float* __restrict__ xn2g,
                                                unsigned long long* __restrict__ masks,
                                                unsigned* __restrict__ cntpart,
                                                unsigned short* __restrict__ lfrag) {
    __shared__ unsigned short xt[16][1040];   // row stride 2080 B: 16B aligned for b128
    __shared__ unsigned cnt[NC];
    __shared__ unsigned long long smask[64];
    int t = threadIdx.x;
    if (blockIdx.x < 1024) {
        int rt = blockIdx.x;
        int r = t >> 4, cpos = t & 15;
        const float4* src = (const float4*)(x + ((size_t)rt * 16 + r) * NDIM) + cpos;
        // batch ALL 16 loads first: ~16 KB in flight per wave -> hide HBM latency
        float4 f[16];
#pragma unroll
        for (int i = 0; i < 16; ++i) f[i] = src[i * 16];
        float sq = 0.f;
#pragma unroll
        for (int i = 0; i < 16; ++i) {
            sq += f[i].x * f[i].x + f[i].y * f[i].y + f[i].z * f[i].z + f[i].w * f[i].w;
            *(uint2*)&xt[r][cpos * 4 + i * 64] = make_uint2(pk2(f[i].x, f[i].y), pk2(f[i].z, f[i].w));
        }
#pragma unroll
        for (int m = 1; m < 16; m <<= 1) sq += __shfl_xor(sq, m, 16);
        if (cpos == 0) xn2g[rt * 16 + r] = sq;
        __syncthreads();
        // xAfrag repack (vector b128 LDS reads, coalesced stores)
        {
            int slot = t & 63, wv = t >> 6;
            int q = slot >> 4, col = slot & 15;
#pragma unroll
            for (int s = 0; s < 8; ++s) {
                int kb = s * 4 + wv;
                uint4 v = *(const uint4*)&xt[col][kb * 32 + q * 8];
                ((uint4*)xAfrag)[((size_t)rt * 32 + kb) * 64 + slot] = v;
            }
        }
        // xcol repack: 8x8 bf16 in-register transpose via v_perm (no scalar LDS reads)
        {
            int rh8 = (t & 1) * 8, dg = t >> 1;   // 2 row-halves x 128 dim-groups
            uint4 R[8];
#pragma unroll
            for (int j = 0; j < 8; ++j) R[j] = *(const uint4*)&xt[rh8 + j][dg * 8];
            uint4* dst = (uint4*)xcol + (size_t)rt * 2048 + t * 8;
#pragma unroll
            for (int p = 0; p < 4; ++p) {
                unsigned lo[4], hi[4];
#pragma unroll
                for (int jj = 0; jj < 4; ++jj) {
                    unsigned A0 = ((const unsigned*)&R[2 * jj])[p];
                    unsigned B0 = ((const unsigned*)&R[2 * jj + 1])[p];
                    lo[jj] = __builtin_amdgcn_perm(B0, A0, 0x05040100u); // (rowE.lo16, rowO.lo16)
                    hi[jj] = __builtin_amdgcn_perm(B0, A0, 0x07060302u); // (rowE.hi16, rowO.hi16)
                }
                dst[2 * p]     = make_uint4(lo[0], lo[1], lo[2], lo[3]); // dim dg*8+2p  : rows 0..7
                dst[2 * p + 1] = make_uint4(hi[0], hi[1], hi[2], hi[3]); // dim dg*8+2p+1: rows 0..7
            }
        }
        return;
    }
    // ---- label path ----
    int bid = blockIdx.x - 1024;
    if (t < NC) cnt[t] = 0;
    __syncthreads();
    int wave = t >> 6, lane = t & 63;
    int rowblock = bid * 64;
    unsigned creg = 0, zreg = 0;
#pragma unroll 4
    for (int p = 0; p < 16; ++p) {
        int row = rowblock + p * 4 + wave;
        int v = label[row * NLAB + lane];
        unsigned long long m = __ballot(v != 0);
        creg += (unsigned)((m >> lane) & 1ull);
        if (lane == 0) {
            masks[row] = m;
            smask[p * 4 + wave] = m;
            zreg += (m == 0ull) ? 1u : 0u;
        }
    }
    atomicAdd(&cnt[lane], creg);
    if (lane == 0 && zreg) atomicAdd(&cnt[64], zreg);
    __syncthreads();
    if (t < 80) cntpart[bid * 80 + t] = (t < NC) ? cnt[t] : 0u;
    for (int pid = t; pid < 640; pid += 256) {
        int rt2l = pid / 320, rem = pid % 320;
        int ct = rem >> 6, ln = rem & 63;
        int q = ln >> 4, col = ln & 15;
        int c = ct * 16 + col;
        int rbase = rt2l * 32 + q * 8;
        unsigned pk[4];
#pragma unroll
        for (int jp = 0; jp < 4; ++jp) {
            unsigned long long m0 = smask[rbase + jp * 2], m1 = smask[rbase + jp * 2 + 1];
            unsigned b0, b1;
            if (c < 64)       { b0 = (unsigned)((m0 >> c) & 1ull); b1 = (unsigned)((m1 >> c) & 1ull); }
            else if (c == 64) { b0 = (m0 == 0ull); b1 = (m1 == 0ull); }
            else              { b0 = 0u; b1 = 0u; }
            pk[jp] = (b0 ? 0x3F80u : 0u) | (b1 ? 0x3F800000u : 0u);
        }
        uint4 w = make_uint4(pk[0], pk[1], pk[2], pk[3]);
        ((uint4*)lfrag)[((size_t)(bid * 2 + rt2l) * 5 + ct) * 64 + ln] = w;
    }
}

// ---- K2: sums = labT @ x; 2-set ping-pong, barrier-free; grid = 16 * kslices ----
__global__ __launch_bounds__(256) void k2_sums(const unsigned short* __restrict__ xcol,
                                               const unsigned short* __restrict__ lfrag,
                                               float* __restrict__ partial,
                                               int kslices) {
    int t = threadIdx.x, wave = t >> 6, lane = t & 63;
    int q = lane >> 4, col = lane & 15;
    int dgroup = blockIdx.x & 15, ks = blockIdx.x >> 4;
    int nkb = (NROWS / kslices) >> 5;
    int kb0 = ks * nkb;
    int d = dgroup * 64 + wave * 16 + col;
    const uint4* B = (const uint4*)xcol;
    const uint4* A = (const uint4*)lfrag;
    // new xcol layout: [rt16][dgrp128][rh2][dlow8] of uint4 (8 rows of one dim)
    size_t bidx0 = (size_t)((d >> 3) * 16 + (q & 1) * 8 + (d & 7));
    int qh = q >> 1;

    float4v acc[5];
#pragma unroll
    for (int ct = 0; ct < 5; ++ct) acc[ct] = (float4v){0.f, 0.f, 0.f, 0.f};

    uint4 b0 = B[(size_t)((kb0 + 0) * 2 + qh) * 2048 + bidx0];
    uint4 a0[5];
#pragma unroll
    for (int ct = 0; ct < 5; ++ct) a0[ct] = A[((size_t)(kb0 + 0) * 5 + ct) * 64 + lane];
    uint4 b1 = B[(size_t)((kb0 + 1) * 2 + qh) * 2048 + bidx0];
    uint4 a1[5];
#pragma unroll
    for (int ct = 0; ct < 5; ++ct) a1[ct] = A[((size_t)(kb0 + 1) * 5 + ct) * 64 + lane];

    for (int i = 0; i < nkb; i += 2) {
        int p2 = i + 2 < nkb ? kb0 + i + 2 : kb0 + i;
        int p3 = i + 3 < nkb ? kb0 + i + 3 : kb0 + i + 1;
        {
            short8 bf = __builtin_bit_cast(short8, b0);
#pragma unroll
            for (int ct = 0; ct < 5; ++ct) {
                short8 af = __builtin_bit_cast(short8, a0[ct]);
                acc[ct] = __builtin_amdgcn_mfma_f32_16x16x32_bf16(af, bf, acc[ct], 0, 0, 0);
            }
            b0 = B[(size_t)(p2 * 2 + qh) * 2048 + bidx0];
#pragma unroll
            for (int ct = 0; ct < 5; ++ct) a0[ct] = A[((size_t)p2 * 5 + ct) * 64 + lane];
        }
        {
            short8 bf = __builtin_bit_cast(short8, b1);
#pragma unroll
            for (int ct = 0; ct < 5; ++ct) {
                short8 af = __builtin_bit_cast(short8, a1[ct]);
                acc[ct] = __builtin_amdgcn_mfma_f32_16x16x32_bf16(af, bf, acc[ct], 0, 0, 0);
            }
            b1 = B[(size_t)(p3 * 2 + qh) * 2048 + bidx0];
#pragma unroll
            for (int ct = 0; ct < 5; ++ct) a1[ct] = A[((size_t)p3 * 5 + ct) * 64 + lane];
        }
    }
    float* pb = partial + (size_t)ks * CPAD * NDIM;
#pragma unroll
    for (int ct = 0; ct < 5; ++ct)
#pragma unroll
        for (int reg = 0; reg < 4; ++reg)
            pb[(size_t)(ct * 16 + q * 4 + reg) * NDIM + d] = acc[ct][reg];
}

// ---- K2bA: 320 blocks (c, dquad); reduce slices -> raw anchor + raw norm2 parts ----
__global__ __launch_bounds__(256) void k2bA(const float* __restrict__ partial,
                                            int kslices,
                                            float* __restrict__ anchor_raw,
                                            float* __restrict__ norm2part) {
    __shared__ float red[4];
    int c = blockIdx.x >> 2, dq = blockIdx.x & 3, t = threadIdx.x;
    int d = dq * 256 + t;
    const float* p = partial + (size_t)c * NDIM + d;
    float s = 0.f;
#pragma unroll 8
    for (int sl = 0; sl < kslices; ++sl) s += p[(size_t)sl * CPAD * NDIM];
    anchor_raw[(size_t)c * NDIM + d] = s;
    float ss = s * s;
#pragma unroll
    for (int m = 32; m >= 1; m >>= 1) ss += __shfl_xor(ss, m, 64);
    if ((t & 63) == 0) red[t >> 6] = ss;
    __syncthreads();
    if (t == 0) norm2part[blockIdx.x] = red[0] + red[1] + red[2] + red[3];
}

// ---- K2bB: 80 blocks x 1024 thr; counts + unit anchors (B-frag) + scale ----
__global__ __launch_bounds__(1024) void k2bB(const float* __restrict__ wptr,
                                             const unsigned* __restrict__ cntpart,
                                             const float* __restrict__ anchor_raw,
                                             const float* __restrict__ norm2part,
                                             unsigned short* __restrict__ bfrag,
                                             float* __restrict__ scale,
                                             unsigned char* __restrict__ actB,
                                             unsigned* __restrict__ countsF,
                                             float* __restrict__ wsum) {
    int c = blockIdx.x, t = threadIdx.x;
    __shared__ float red[16];
    __shared__ unsigned credu[4];
    __shared__ float bcast[1];
    if (c == 0 && t == 512) *wsum = 0.f;
    if (t < 256) {
        unsigned cv = cntpart[t * 80 + c];
#pragma unroll
        for (int m = 32; m >= 1; m >>= 1) cv += __shfl_xor(cv, m, 64);
        if ((t & 63) == 0) credu[t >> 6] = cv;
    }
    if (t == 0)
        bcast[0] = sqrtf(norm2part[c * 4] + norm2part[c * 4 + 1] +
                         norm2part[c * 4 + 2] + norm2part[c * 4 + 3]);
    __syncthreads();
    unsigned cnt = credu[0] + credu[1] + credu[2] + credu[3];
    float invc = 1.0f / (float)(cnt > 0u ? cnt : 1u);
    float a = anchor_raw[(size_t)c * NDIM + t] * invc;       // mean
    float an = fmaxf(bcast[0] * invc, 1e-8f);                // max(||mean||, eps); ||mean||=||raw||/cnt
    unsigned short h = bf16u(a / an);
    // B-frag slot for (c, d=t)
    int ct = c >> 4, colc = c & 15;
    int kb = t >> 5, q = (t >> 3) & 3, j0 = t & 7;
    bfrag[((((size_t)ct * 32 + kb) * 64) + q * 16 + colc) * 8 + j0] = h;
    float hv = __bfloat162float(__builtin_bit_cast(__hip_bfloat16, h));
    float nb2 = hv * hv;
#pragma unroll
    for (int m = 32; m >= 1; m >>= 1) nb2 += __shfl_xor(nb2, m, 64);
    if ((t & 63) == 0) red[t >> 6] = nb2;
    __syncthreads();
    if (t == 0) {
        float n2 = 0.f;
#pragma unroll
        for (int j = 0; j < 16; ++j) n2 += red[j];
        scale[c] = (n2 > 0.f) ? (wptr[0] / sqrtf(n2)) : 0.f;
        actB[c] = (cnt > 0u) ? 1 : 0;
        countsF[c] = cnt;
    }
}

// ---- K3: cos GEMM; block = one 16-row tile, 4 waves K-split x8 kb each;
// LDS combine, wave0 fused softmax loss. 1024 blocks -> 16 waves/CU ----
__global__ __launch_bounds__(256) void k3_loss(const unsigned short* __restrict__ xAfrag,
                                               const unsigned short* __restrict__ bfrag,
                                               const float* __restrict__ xn2g,
                                               const unsigned long long* __restrict__ masks,
                                               const unsigned char* __restrict__ actB,
                                               const float* __restrict__ scale,
                                               const float* __restrict__ bptr,
                                               float* __restrict__ wsum) {
    __shared__ float redsm[3][64][21];   // stride 21: gcd(21,32)=1 -> conflict-free
    int t = threadIdx.x, wave = t >> 6, lane = t & 63;
    int q = lane >> 4, col = lane & 15;
    int rt = blockIdx.x;
    int rowbase = rt * 16;
    const uint4* A = (const uint4*)xAfrag + (size_t)rt * 32 * 64 + lane;
    const uint4* Bp = (const uint4*)bfrag + lane;
    int kb0 = wave * 8;

    float4v acc[5];
#pragma unroll
    for (int ct = 0; ct < 5; ++ct) acc[ct] = (float4v){0.f, 0.f, 0.f, 0.f};

    uint4 a0 = A[(size_t)(kb0 + 0) * 64], a1 = A[(size_t)(kb0 + 1) * 64];
    uint4 b0[5], b1[5];
#pragma unroll
    for (int ct = 0; ct < 5; ++ct) b0[ct] = Bp[(size_t)(ct * 32 + kb0 + 0) * 64];
#pragma unroll
    for (int ct = 0; ct < 5; ++ct) b1[ct] = Bp[(size_t)(ct * 32 + kb0 + 1) * 64];

    for (int s = 0; s < 8; s += 2) {
        int p2 = s + 2 < 8 ? kb0 + s + 2 : kb0 + s;
        int p3 = s + 3 < 8 ? kb0 + s + 3 : kb0 + s + 1;
        {
            short8 af = __builtin_bit_cast(short8, a0);
#pragma unroll
            for (int ct = 0; ct < 5; ++ct) {
                short8 bf = __builtin_bit_cast(short8, b0[ct]);
                acc[ct] = __builtin_amdgcn_mfma_f32_16x16x32_bf16(af, bf, acc[ct], 0, 0, 0);
            }
            a0 = A[(size_t)p2 * 64];
#pragma unroll
            for (int ct = 0; ct < 5; ++ct) b0[ct] = Bp[(size_t)(ct * 32 + p2) * 64];
        }
        {
            short8 af = __builtin_bit_cast(short8, a1);
#pragma unroll
            for (int ct = 0; ct < 5; ++ct) {
                short8 bf = __builtin_bit_cast(short8, b1[ct]);
                acc[ct] = __builtin_amdgcn_mfma_f32_16x16x32_bf16(af, bf, acc[ct], 0, 0, 0);
            }
            a1 = A[(size_t)p3 * 64];
#pragma unroll
            for (int ct = 0; ct < 5; ++ct) b1[ct] = Bp[(size_t)(ct * 32 + p3) * 64];
        }
    }

    if (wave) {
#pragma unroll
        for (int ct = 0; ct < 5; ++ct)
#pragma unroll
            for (int reg = 0; reg < 4; ++reg)
                redsm[wave - 1][lane][ct * 4 + reg] = acc[ct][reg];
    }
    __syncthreads();
    if (wave != 0) return;
#pragma unroll
    for (int w = 0; w < 3; ++w)
#pragma unroll
        for (int ct = 0; ct < 5; ++ct)
#pragma unroll
            for (int reg = 0; reg < 4; ++reg)
                acc[ct][reg] += redsm[w][lane][ct * 4 + reg];

    float bv = bptr[0];
    float sc[5]; unsigned char ab[5];
#pragma unroll
    for (int ct = 0; ct < 5; ++ct) { sc[ct] = scale[ct * 16 + col]; ab[ct] = actB[ct * 16 + col]; }

    float contrib = 0.f;
#pragma unroll
    for (int reg = 0; reg < 4; ++reg) {
        int rl = q * 4 + reg;
        int row = rowbase + rl;
        float inv = 1.0f / fmaxf(sqrtf(xn2g[row]), 1e-8f);
        unsigned long long mask = masks[row];
        float v[5]; float lmax = -1e30f;
#pragma unroll
        for (int ct = 0; ct < 5; ++ct) {
            float lg = acc[ct][reg] * sc[ct] * inv + bv;   // w*cos + b
            v[ct] = ab[ct] ? lg : -1e30f;
            lmax = fmaxf(lmax, v[ct]);
        }
#pragma unroll
        for (int m = 1; m < 16; m <<= 1) lmax = fmaxf(lmax, __shfl_xor(lmax, m, 16));
        float es = 0.f;
#pragma unroll
        for (int ct = 0; ct < 5; ++ct) es += expf(v[ct] - lmax);
#pragma unroll
        for (int m = 1; m < 16; m <<= 1) es += __shfl_xor(es, m, 16);
        float lse = lmax + logf(es);
        float ps = 0.f;
#pragma unroll
        for (int ct = 0; ct < 5; ++ct) {
            int c = ct * 16 + col;
            bool pos = (c < 64) ? (((mask >> c) & 1ull) != 0ull)
                                : ((c == 64) ? (mask == 0ull) : false);
            ps += pos ? v[ct] : 0.f;
        }
#pragma unroll
        for (int m = 1; m < 16; m <<= 1) ps += __shfl_xor(ps, m, 16);
        float npos = mask ? (float)__popcll(mask) : 1.0f;
        float crow = ps - npos * lse;
        if (col == 0) contrib += crow;
    }
#pragma unroll
    for (int m = 1; m < 64; m <<= 1) contrib += __shfl_xor(contrib, m, 64);
    if (lane == 0) atomicAdd(wsum, contrib);
}

// ---- K4: loss = -sum(logp over positive pairs) / n_pairs ----
__global__ void k4_final(const unsigned* __restrict__ countsF,
                         const float* __restrict__ wsum,
                         float* __restrict__ out) {
    if (threadIdx.x == 0 && blockIdx.x == 0) {
        float np = 0.f;
        for (int c = 0; c < NC; ++c) np += (float)countsF[c];
        out[0] = -wsum[0] / np;
    }
}

extern "C" void kernel_launch(void* const* d_in, const int* in_sizes, int n_in,
                              void* d_out, int out_size, void* d_ws, size_t ws_size,
                              hipStream_t stream) {
    (void)in_sizes; (void)n_in; (void)out_size;
    const float* x = (const float*)d_in[0];
    const int* label = (const int*)d_in[1];
    const float* w = (const float*)d_in[2];
    const float* b = (const float*)d_in[3];

    char* ws = (char*)d_ws;
    float* scale = (float*)(ws + SCALE_B);
    unsigned char* actB = (unsigned char*)(ws + ACTB_B);
    float* wsum = (float*)(ws + WSUM_B);
    unsigned* countsF = (unsigned*)(ws + CNTF_B);
    unsigned* cntpart = (unsigned*)(ws + CNTP_B);
    unsigned long long* masks = (unsigned long long*)(ws + MASK_B);
    float* xn2g = (float*)(ws + XN2_B);
    unsigned short* lfrag = (unsigned short*)(ws + LFRAG_B);
    unsigned short* bfrag = (unsigned short*)(ws + BFRAG_B);
    unsigned short* xAfrag = (unsigned short*)(ws + XAF_B);
    unsigned short* xcol = (unsigned short*)(ws + XCOL_B);
    float* partial = (float*)(ws + PART_B);

    int kslices = 64;
    while (kslices > 8 && PART_B + (size_t)kslices * SLAB + ANCH_SZ + NRM_SZ > ws_size)
        kslices >>= 1;
    float* anchor_raw = (float*)(ws + PART_B + (size_t)kslices * SLAB);
    float* norm2part = anchor_raw + CPAD * NDIM;

    hipLaunchKernelGGL(k01_prep, dim3(1024 + 256), dim3(256), 0, stream,
                       x, label, xAfrag, xcol, xn2g, masks, cntpart, lfrag);
    hipLaunchKernelGGL(k2_sums, dim3(16 * kslices), dim3(256), 0, stream,
                       xcol, lfrag, partial, kslices);
    hipLaunchKernelGGL(k2bA, dim3(CPAD * 4), dim3(256), 0, stream,
                       partial, kslices, anchor_raw, norm2part);
    hipLaunchKernelGGL(k2bB, dim3(CPAD), dim3(1024), 0, stream,
                       w, cntpart, anchor_raw, norm2part, bfrag, scale, actB, countsF, wsum);
    hipLaunchKernelGGL(k3_loss, dim3(NROWS / 16), dim3(256), 0, stream,
                       xAfrag, bfrag, xn2g, masks, actB, scale, b, wsum);
    hipLaunchKernelGGL(k4_final, dim3(1), dim3(64), 0, stream, countsF, wsum, (float*)d_out);
}

// Round 2
// 168.528 us; speedup vs baseline: 1.0218x; 1.0218x over previous
//
#include <hip/hip_runtime.h>
#include <hip/hip_bf16.h>
#include <stdint.h>

#define NROWS 16384
#define NDIM  1024
#define NLAB  64
#define NC    65
#define CPAD  80

typedef float float4v __attribute__((ext_vector_type(4)));
typedef short short8  __attribute__((ext_vector_type(8)));

// ---- workspace layout (bytes); nothing needs pre-zeroing ----
static constexpr size_t SCALE_B = 0;         // 80 f32 (w/||abf_c||)
static constexpr size_t ACTB_B  = 320;       // 80 u8 active flags
static constexpr size_t WSUM_B  = 400;       // f32 loss accumulator (zeroed by k2bB)
static constexpr size_t CNTF_B  = 448;       // 80 u32 counts (written by k2bB)
static constexpr size_t CNTP_B  = 1024;      // 256 x 80 u32 per-block count slabs
static constexpr size_t MASK_B  = 83968;     // 16384 u64 row masks
static constexpr size_t XN2_B   = 215040;    // 16384 f32 row norms^2
static constexpr size_t LFRAG_B = 280576;    // labT bf16, A-frag layout (2.6 MB)
static constexpr size_t BFRAG_B = 2902016;   // unit anchors bf16, B-frag layout
static constexpr size_t XAF_B   = 3065856;   // x bf16, A-frag layout (32 MB)
static constexpr size_t PART_B  = 70174720;  // kslices*80*1024 f32 partials
static constexpr size_t SLAB    = (size_t)CPAD * NDIM * 4;
static constexpr size_t ANCH_SZ = (size_t)CPAD * NDIM * 4;   // raw anchor sums f32
static constexpr size_t NRM_SZ  = (size_t)CPAD * 4 * 4;      // 320 f32 norm2 partials

__device__ __forceinline__ unsigned short bf16u(float f) {
    __hip_bfloat16 h = __float2bfloat16(f);
    return __builtin_bit_cast(unsigned short, h);
}
__device__ __forceinline__ unsigned pk2(float a, float b) {
    return (unsigned)bf16u(a) | ((unsigned)bf16u(b) << 16);
}

// ---- K01: blocks 0..1023 = x prep (xAfrag + xn2, all in-register);
//          blocks 1024..1279 = labels. No big LDS tile, no transpose. ----
__global__ __launch_bounds__(256, 4) void k01_prep(const float* __restrict__ x,
                                                   const int* __restrict__ label,
                                                   unsigned short* __restrict__ xAfrag,
                                                   float* __restrict__ xn2g,
                                                   unsigned long long* __restrict__ masks,
                                                   unsigned* __restrict__ cntpart,
                                                   unsigned short* __restrict__ lfrag) {
    __shared__ unsigned cnt[NC];
    __shared__ unsigned long long smask[64];
    __shared__ float red[4][16];
    int t = threadIdx.x;
    if (blockIdx.x < 1024) {
        int rt = blockIdx.x;
        int w = t >> 6, lane = t & 63, q = lane >> 4, col = lane & 15;
        // lane (q,col) of wave w owns row rt*16+col, dims w*256 + kb*32 + q*8 .. +7
        const float* rowp = x + ((size_t)rt * 16 + col) * NDIM;
        uint4* dst = (uint4*)xAfrag + ((size_t)rt * 32 + w * 8) * 64 + lane;
        float sq = 0.f;
#pragma unroll
        for (int kb = 0; kb < 8; ++kb) {
            int d0 = w * 256 + kb * 32 + q * 8;
            float4 fa = *(const float4*)(rowp + d0);
            float4 fb = *(const float4*)(rowp + d0 + 4);
            sq += fa.x * fa.x + fa.y * fa.y + fa.z * fa.z + fa.w * fa.w
                + fb.x * fb.x + fb.y * fb.y + fb.z * fb.z + fb.w * fb.w;
            uint4 v;
            v.x = pk2(fa.x, fa.y); v.y = pk2(fa.z, fa.w);
            v.z = pk2(fb.x, fb.y); v.w = pk2(fb.z, fb.w);
            dst[kb * 64] = v;   // 64 lanes x 16 B contiguous per instr
        }
        // row col's partial lives in lanes {col, col+16, col+32, col+48}
        sq += __shfl_xor(sq, 16, 64);
        sq += __shfl_xor(sq, 32, 64);
        if (q == 0) red[w][col] = sq;
        __syncthreads();
        if (t < 16) xn2g[rt * 16 + t] = red[0][t] + red[1][t] + red[2][t] + red[3][t];
        return;
    }
    // ---- label path ----
    int bid = blockIdx.x - 1024;
    if (t < NC) cnt[t] = 0;
    __syncthreads();
    int wave = t >> 6, lane = t & 63;
    int rowblock = bid * 64;
    unsigned creg = 0, zreg = 0;
#pragma unroll 4
    for (int p = 0; p < 16; ++p) {
        int row = rowblock + p * 4 + wave;
        int v = label[row * NLAB + lane];
        unsigned long long m = __ballot(v != 0);
        creg += (unsigned)((m >> lane) & 1ull);
        if (lane == 0) {
            masks[row] = m;
            smask[p * 4 + wave] = m;
            zreg += (m == 0ull) ? 1u : 0u;
        }
    }
    atomicAdd(&cnt[lane], creg);
    if (lane == 0 && zreg) atomicAdd(&cnt[64], zreg);
    __syncthreads();
    if (t < 80) cntpart[bid * 80 + t] = (t < NC) ? cnt[t] : 0u;
    for (int pid = t; pid < 640; pid += 256) {
        int rt2l = pid / 320, rem = pid % 320;
        int ct = rem >> 6, ln = rem & 63;
        int q = ln >> 4, col = ln & 15;
        int c = ct * 16 + col;
        int rbase = rt2l * 32 + q * 8;
        unsigned pk[4];
#pragma unroll
        for (int jp = 0; jp < 4; ++jp) {
            unsigned long long m0 = smask[rbase + jp * 2], m1 = smask[rbase + jp * 2 + 1];
            unsigned b0, b1;
            if (c < 64)       { b0 = (unsigned)((m0 >> c) & 1ull); b1 = (unsigned)((m1 >> c) & 1ull); }
            else if (c == 64) { b0 = (m0 == 0ull); b1 = (m1 == 0ull); }
            else              { b0 = 0u; b1 = 0u; }
            pk[jp] = (b0 ? 0x3F80u : 0u) | (b1 ? 0x3F800000u : 0u);
        }
        uint4 w = make_uint4(pk[0], pk[1], pk[2], pk[3]);
        ((uint4*)lfrag)[((size_t)(bid * 2 + rt2l) * 5 + ct) * 64 + ln] = w;
    }
}

// ---- K2: sums = labT @ x; B-frag gathered DIRECTLY from f32 x (8 dwords + pack),
// no xcol intermediate. 2-set ping-pong, barrier-free; grid = 16 * kslices ----
__global__ __launch_bounds__(256) void k2_sums(const float* __restrict__ x,
                                               const unsigned short* __restrict__ lfrag,
                                               float* __restrict__ partial,
                                               int kslices) {
    int t = threadIdx.x, wave = t >> 6, lane = t & 63;
    int q = lane >> 4, col = lane & 15;
    int dgroup = blockIdx.x & 15, ks = blockIdx.x >> 4;
    int nkb = (NROWS / kslices) >> 5;
    int kb0 = ks * nkb;
    int d = dgroup * 64 + wave * 16 + col;
    const uint4* A = (const uint4*)lfrag;
    const float* xb = x + d;   // this lane's dim column

    float4v acc[5];
#pragma unroll
    for (int ct = 0; ct < 5; ++ct) acc[ct] = (float4v){0.f, 0.f, 0.f, 0.f};

    float f0[8], f1[8];
    uint4 a0[5], a1[5];
    {
        const float* p = xb + (size_t)(kb0 * 32 + q * 8) * NDIM;
#pragma unroll
        for (int j = 0; j < 8; ++j) f0[j] = p[(size_t)j * NDIM];
#pragma unroll
        for (int ct = 0; ct < 5; ++ct) a0[ct] = A[((size_t)kb0 * 5 + ct) * 64 + lane];
        const float* p1 = xb + (size_t)((kb0 + 1) * 32 + q * 8) * NDIM;
#pragma unroll
        for (int j = 0; j < 8; ++j) f1[j] = p1[(size_t)j * NDIM];
#pragma unroll
        for (int ct = 0; ct < 5; ++ct) a1[ct] = A[((size_t)(kb0 + 1) * 5 + ct) * 64 + lane];
    }

    for (int i = 0; i < nkb; i += 2) {
        int p2 = i + 2 < nkb ? kb0 + i + 2 : kb0 + i;
        int p3 = i + 3 < nkb ? kb0 + i + 3 : kb0 + i + 1;
        {
            uint4 bq;
            bq.x = pk2(f0[0], f0[1]); bq.y = pk2(f0[2], f0[3]);
            bq.z = pk2(f0[4], f0[5]); bq.w = pk2(f0[6], f0[7]);
            short8 bf = __builtin_bit_cast(short8, bq);
#pragma unroll
            for (int ct = 0; ct < 5; ++ct) {
                short8 af = __builtin_bit_cast(short8, a0[ct]);
                acc[ct] = __builtin_amdgcn_mfma_f32_16x16x32_bf16(af, bf, acc[ct], 0, 0, 0);
            }
            const float* p = xb + (size_t)(p2 * 32 + q * 8) * NDIM;
#pragma unroll
            for (int j = 0; j < 8; ++j) f0[j] = p[(size_t)j * NDIM];
#pragma unroll
            for (int ct = 0; ct < 5; ++ct) a0[ct] = A[((size_t)p2 * 5 + ct) * 64 + lane];
        }
        {
            uint4 bq;
            bq.x = pk2(f1[0], f1[1]); bq.y = pk2(f1[2], f1[3]);
            bq.z = pk2(f1[4], f1[5]); bq.w = pk2(f1[6], f1[7]);
            short8 bf = __builtin_bit_cast(short8, bq);
#pragma unroll
            for (int ct = 0; ct < 5; ++ct) {
                short8 af = __builtin_bit_cast(short8, a1[ct]);
                acc[ct] = __builtin_amdgcn_mfma_f32_16x16x32_bf16(af, bf, acc[ct], 0, 0, 0);
            }
            const float* p = xb + (size_t)(p3 * 32 + q * 8) * NDIM;
#pragma unroll
            for (int j = 0; j < 8; ++j) f1[j] = p[(size_t)j * NDIM];
#pragma unroll
            for (int ct = 0; ct < 5; ++ct) a1[ct] = A[((size_t)p3 * 5 + ct) * 64 + lane];
        }
    }
    float* pb = partial + (size_t)ks * CPAD * NDIM;
#pragma unroll
    for (int ct = 0; ct < 5; ++ct)
#pragma unroll
        for (int reg = 0; reg < 4; ++reg)
            pb[(size_t)(ct * 16 + q * 4 + reg) * NDIM + d] = acc[ct][reg];
}

// ---- K2bA: 320 blocks (c, dquad); reduce slices -> raw anchor + raw norm2 parts ----
__global__ __launch_bounds__(256) void k2bA(const float* __restrict__ partial,
                                            int kslices,
                                            float* __restrict__ anchor_raw,
                                            float* __restrict__ norm2part) {
    __shared__ float red[4];
    int c = blockIdx.x >> 2, dq = blockIdx.x & 3, t = threadIdx.x;
    int d = dq * 256 + t;
    const float* p = partial + (size_t)c * NDIM + d;
    float s = 0.f;
#pragma unroll 8
    for (int sl = 0; sl < kslices; ++sl) s += p[(size_t)sl * CPAD * NDIM];
    anchor_raw[(size_t)c * NDIM + d] = s;
    float ss = s * s;
#pragma unroll
    for (int m = 32; m >= 1; m >>= 1) ss += __shfl_xor(ss, m, 64);
    if ((t & 63) == 0) red[t >> 6] = ss;
    __syncthreads();
    if (t == 0) norm2part[blockIdx.x] = red[0] + red[1] + red[2] + red[3];
}

// ---- K2bB: 80 blocks x 1024 thr; counts + unit anchors (B-frag) + scale ----
__global__ __launch_bounds__(1024) void k2bB(const float* __restrict__ wptr,
                                             const unsigned* __restrict__ cntpart,
                                             const float* __restrict__ anchor_raw,
                                             const float* __restrict__ norm2part,
                                             unsigned short* __restrict__ bfrag,
                                             float* __restrict__ scale,
                                             unsigned char* __restrict__ actB,
                                             unsigned* __restrict__ countsF,
                                             float* __restrict__ wsum) {
    int c = blockIdx.x, t = threadIdx.x;
    __shared__ float red[16];
    __shared__ unsigned credu[4];
    __shared__ float bcast[1];
    if (c == 0 && t == 512) *wsum = 0.f;
    if (t < 256) {
        unsigned cv = cntpart[t * 80 + c];
#pragma unroll
        for (int m = 32; m >= 1; m >>= 1) cv += __shfl_xor(cv, m, 64);
        if ((t & 63) == 0) credu[t >> 6] = cv;
    }
    if (t == 0)
        bcast[0] = sqrtf(norm2part[c * 4] + norm2part[c * 4 + 1] +
                         norm2part[c * 4 + 2] + norm2part[c * 4 + 3]);
    __syncthreads();
    unsigned cnt = credu[0] + credu[1] + credu[2] + credu[3];
    float invc = 1.0f / (float)(cnt > 0u ? cnt : 1u);
    float a = anchor_raw[(size_t)c * NDIM + t] * invc;       // mean
    float an = fmaxf(bcast[0] * invc, 1e-8f);                // max(||mean||, eps)
    unsigned short h = bf16u(a / an);
    int ct = c >> 4, colc = c & 15;
    int kb = t >> 5, q = (t >> 3) & 3, j0 = t & 7;
    bfrag[((((size_t)ct * 32 + kb) * 64) + q * 16 + colc) * 8 + j0] = h;
    float hv = __bfloat162float(__builtin_bit_cast(__hip_bfloat16, h));
    float nb2 = hv * hv;
#pragma unroll
    for (int m = 32; m >= 1; m >>= 1) nb2 += __shfl_xor(nb2, m, 64);
    if ((t & 63) == 0) red[t >> 6] = nb2;
    __syncthreads();
    if (t == 0) {
        float n2 = 0.f;
#pragma unroll
        for (int j = 0; j < 16; ++j) n2 += red[j];
        scale[c] = (n2 > 0.f) ? (wptr[0] / sqrtf(n2)) : 0.f;
        actB[c] = (cnt > 0u) ? 1 : 0;
        countsF[c] = cnt;
    }
}

// ---- K3: cos GEMM; block = one 16-row tile, 4 waves K-split x8 kb each;
// LDS combine, wave0 fused softmax loss. 1024 blocks -> 16 waves/CU ----
__global__ __launch_bounds__(256) void k3_loss(const unsigned short* __restrict__ xAfrag,
                                               const unsigned short* __restrict__ bfrag,
                                               const float* __restrict__ xn2g,
                                               const unsigned long long* __restrict__ masks,
                                               const unsigned char* __restrict__ actB,
                                               const float* __restrict__ scale,
                                               const float* __restrict__ bptr,
                                               float* __restrict__ wsum) {
    __shared__ float redsm[3][64][21];   // stride 21: gcd(21,32)=1 -> conflict-free
    int t = threadIdx.x, wave = t >> 6, lane = t & 63;
    int q = lane >> 4, col = lane & 15;
    int rt = blockIdx.x;
    int rowbase = rt * 16;
    const uint4* A = (const uint4*)xAfrag + (size_t)rt * 32 * 64 + lane;
    const uint4* Bp = (const uint4*)bfrag + lane;
    int kb0 = wave * 8;

    float4v acc[5];
#pragma unroll
    for (int ct = 0; ct < 5; ++ct) acc[ct] = (float4v){0.f, 0.f, 0.f, 0.f};

    uint4 a0 = A[(size_t)(kb0 + 0) * 64], a1 = A[(size_t)(kb0 + 1) * 64];
    uint4 b0[5], b1[5];
#pragma unroll
    for (int ct = 0; ct < 5; ++ct) b0[ct] = Bp[(size_t)(ct * 32 + kb0 + 0) * 64];
#pragma unroll
    for (int ct = 0; ct < 5; ++ct) b1[ct] = Bp[(size_t)(ct * 32 + kb0 + 1) * 64];

    for (int s = 0; s < 8; s += 2) {
        int p2 = s + 2 < 8 ? kb0 + s + 2 : kb0 + s;
        int p3 = s + 3 < 8 ? kb0 + s + 3 : kb0 + s + 1;
        {
            short8 af = __builtin_bit_cast(short8, a0);
#pragma unroll
            for (int ct = 0; ct < 5; ++ct) {
                short8 bf = __builtin_bit_cast(short8, b0[ct]);
                acc[ct] = __builtin_amdgcn_mfma_f32_16x16x32_bf16(af, bf, acc[ct], 0, 0, 0);
            }
            a0 = A[(size_t)p2 * 64];
#pragma unroll
            for (int ct = 0; ct < 5; ++ct) b0[ct] = Bp[(size_t)(ct * 32 + p2) * 64];
        }
        {
            short8 af = __builtin_bit_cast(short8, a1);
#pragma unroll
            for (int ct = 0; ct < 5; ++ct) {
                short8 bf = __builtin_bit_cast(short8, b1[ct]);
                acc[ct] = __builtin_amdgcn_mfma_f32_16x16x32_bf16(af, bf, acc[ct], 0, 0, 0);
            }
            a1 = A[(size_t)p3 * 64];
#pragma unroll
            for (int ct = 0; ct < 5; ++ct) b1[ct] = Bp[(size_t)(ct * 32 + p3) * 64];
        }
    }

    if (wave) {
#pragma unroll
        for (int ct = 0; ct < 5; ++ct)
#pragma unroll
            for (int reg = 0; reg < 4; ++reg)
                redsm[wave - 1][lane][ct * 4 + reg] = acc[ct][reg];
    }
    __syncthreads();
    if (wave != 0) return;
#pragma unroll
    for (int w = 0; w < 3; ++w)
#pragma unroll
        for (int ct = 0; ct < 5; ++ct)
#pragma unroll
            for (int reg = 0; reg < 4; ++reg)
                acc[ct][reg] += redsm[w][lane][ct * 4 + reg];

    float bv = bptr[0];
    float sc[5]; unsigned char ab[5];
#pragma unroll
    for (int ct = 0; ct < 5; ++ct) { sc[ct] = scale[ct * 16 + col]; ab[ct] = actB[ct * 16 + col]; }

    float contrib = 0.f;
#pragma unroll
    for (int reg = 0; reg < 4; ++reg) {
        int rl = q * 4 + reg;
        int row = rowbase + rl;
        float inv = 1.0f / fmaxf(sqrtf(xn2g[row]), 1e-8f);
        unsigned long long mask = masks[row];
        float v[5]; float lmax = -1e30f;
#pragma unroll
        for (int ct = 0; ct < 5; ++ct) {
            float lg = acc[ct][reg] * sc[ct] * inv + bv;   // w*cos + b
            v[ct] = ab[ct] ? lg : -1e30f;
            lmax = fmaxf(lmax, v[ct]);
        }
#pragma unroll
        for (int m = 1; m < 16; m <<= 1) lmax = fmaxf(lmax, __shfl_xor(lmax, m, 16));
        float es = 0.f;
#pragma unroll
        for (int ct = 0; ct < 5; ++ct) es += expf(v[ct] - lmax);
#pragma unroll
        for (int m = 1; m < 16; m <<= 1) es += __shfl_xor(es, m, 16);
        float lse = lmax + logf(es);
        float ps = 0.f;
#pragma unroll
        for (int ct = 0; ct < 5; ++ct) {
            int c = ct * 16 + col;
            bool pos = (c < 64) ? (((mask >> c) & 1ull) != 0ull)
                                : ((c == 64) ? (mask == 0ull) : false);
            ps += pos ? v[ct] : 0.f;
        }
#pragma unroll
        for (int m = 1; m < 16; m <<= 1) ps += __shfl_xor(ps, m, 16);
        float npos = mask ? (float)__popcll(mask) : 1.0f;
        float crow = ps - npos * lse;
        if (col == 0) contrib += crow;
    }
#pragma unroll
    for (int m = 1; m < 64; m <<= 1) contrib += __shfl_xor(contrib, m, 64);
    if (lane == 0) atomicAdd(wsum, contrib);
}

// ---- K4: loss = -sum(logp over positive pairs) / n_pairs ----
__global__ void k4_final(const unsigned* __restrict__ countsF,
                         const float* __restrict__ wsum,
                         float* __restrict__ out) {
    if (threadIdx.x == 0 && blockIdx.x == 0) {
        float np = 0.f;
        for (int c = 0; c < NC; ++c) np += (float)countsF[c];
        out[0] = -wsum[0] / np;
    }
}

extern "C" void kernel_launch(void* const* d_in, const int* in_sizes, int n_in,
                              void* d_out, int out_size, void* d_ws, size_t ws_size,
                              hipStream_t stream) {
    (void)in_sizes; (void)n_in; (void)out_size;
    const float* x = (const float*)d_in[0];
    const int* label = (const int*)d_in[1];
    const float* w = (const float*)d_in[2];
    const float* b = (const float*)d_in[3];

    char* ws = (char*)d_ws;
    float* scale = (float*)(ws + SCALE_B);
    unsigned char* actB = (unsigned char*)(ws + ACTB_B);
    float* wsum = (float*)(ws + WSUM_B);
    unsigned* countsF = (unsigned*)(ws + CNTF_B);
    unsigned* cntpart = (unsigned*)(ws + CNTP_B);
    unsigned long long* masks = (unsigned long long*)(ws + MASK_B);
    float* xn2g = (float*)(ws + XN2_B);
    unsigned short* lfrag = (unsigned short*)(ws + LFRAG_B);
    unsigned short* bfrag = (unsigned short*)(ws + BFRAG_B);
    unsigned short* xAfrag = (unsigned short*)(ws + XAF_B);
    float* partial = (float*)(ws + PART_B);

    int kslices = 64;
    while (kslices > 8 && PART_B + (size_t)kslices * SLAB + ANCH_SZ + NRM_SZ > ws_size)
        kslices >>= 1;
    float* anchor_raw = (float*)(ws + PART_B + (size_t)kslices * SLAB);
    float* norm2part = anchor_raw + CPAD * NDIM;

    hipLaunchKernelGGL(k01_prep, dim3(1024 + 256), dim3(256), 0, stream,
                       x, label, xAfrag, xn2g, masks, cntpart, lfrag);
    hipLaunchKernelGGL(k2_sums, dim3(16 * kslices), dim3(256), 0, stream,
                       x, lfrag, partial, kslices);
    hipLaunchKernelGGL(k2bA, dim3(CPAD * 4), dim3(256), 0, stream,
                       partial, kslices, anchor_raw, norm2part);
    hipLaunchKernelGGL(k2bB, dim3(CPAD), dim3(1024), 0, stream,
                       w, cntpart, anchor_raw, norm2part, bfrag, scale, actB, countsF, wsum);
    hipLaunchKernelGGL(k3_loss, dim3(NROWS / 16), dim3(256), 0, stream,
                       xAfrag, bfrag, xn2g, masks, actB, scale, b, wsum);
    hipLaunchKernelGGL(k4_final, dim3(1), dim3(64), 0, stream, countsF, wsum, (float*)d_out);
}